// Round 1
// baseline (3648.634 us; speedup 1.0000x reference)
//
#include <hip/hip_runtime.h>
#include <stdint.h>

typedef unsigned short u16;
typedef unsigned int   u32;
typedef __attribute__((ext_vector_type(8))) short short8;
typedef __attribute__((ext_vector_type(4))) float f32x4;

#define CAP   52
#define CAPW  26

__device__ __forceinline__ u16 rne_bf16(float f){
  u32 u = __float_as_uint(f);
  u32 r = (u + 0x7fffu + ((u >> 16) & 1u)) >> 16;
  return (u16)r;
}
__device__ __forceinline__ float bf16_to_f(u16 h){
  return __uint_as_float(((u32)h) << 16);
}
__device__ __forceinline__ float tanh_fast(float x){
  float e = __expf(2.0f * x);
  return 1.0f - 2.0f / (e + 1.0f);
}

// ---------------------------------------------------------------------------
// A-pack: [xhi fbhi | xlo fblo], row m = b*1024+s, K=2048 bf16 bits
// ---------------------------------------------------------------------------
__global__ __launch_bounds__(256) void pack_a_k(const float* __restrict__ x,
                                                const float* __restrict__ fb,
                                                u16* __restrict__ A){
  int idx = blockIdx.x * 256 + threadIdx.x;          // 16384*512
  int m = idx >> 9, d = idx & 511;
  float xv = x[idx];
  float fv = fb[idx];
  u16 xh = rne_bf16(xv); u16 xl = rne_bf16(xv - bf16_to_f(xh));
  u16 fh = rne_bf16(fv); u16 fl = rne_bf16(fv - bf16_to_f(fh));
  size_t base = (size_t)m * 2048;
  A[base + d]        = xh;
  A[base + 512 + d]  = fh;
  A[base + 1024 + d] = xl;
  A[base + 1536 + d] = fl;
}

// ---------------------------------------------------------------------------
// B-pack: K=3072: [Winhi Wfbhi | Winhi Wfbhi | Winlo Wfblo]
// segs pair with A(keff): seg0: Ahi*Bhi, seg1: Alo*Bhi, seg2: Ahi*Blo
// ---------------------------------------------------------------------------
__global__ __launch_bounds__(256) void pack_b_k(const float* __restrict__ Win,
                                                const float* __restrict__ Wfb,
                                                u16* __restrict__ Bm){
  int idx = blockIdx.x * 256 + threadIdx.x;          // 2048*512
  int n = idx >> 9, d = idx & 511;
  float iv = Win[idx];
  float fv = Wfb[idx];
  u16 ih = rne_bf16(iv); u16 il = rne_bf16(iv - bf16_to_f(ih));
  u16 fh = rne_bf16(fv); u16 fl = rne_bf16(fv - bf16_to_f(fh));
  size_t base = (size_t)n * 3072;
  Bm[base + d]        = ih;
  Bm[base + 512 + d]  = fh;
  Bm[base + 1024 + d] = ih;
  Bm[base + 1536 + d] = fh;
  Bm[base + 2048 + d] = il;
  Bm[base + 2560 + d] = fl;
}

// ---------------------------------------------------------------------------
// Drive GEMM: C[m][n] = sum_k A[m][keff]*B[n][k], M=16384,N=2048,K=3072
// 128x128 tile, 256 thr (4 waves), 16x16x32 bf16 MFMA, global_load_lds 16B
// Writes fp32 drive directly into d_out (B,S,N)
// ---------------------------------------------------------------------------
#define GLDS(gp, lp) __builtin_amdgcn_global_load_lds( \
    (const __attribute__((address_space(1))) void*)(gp), \
    (__attribute__((address_space(3))) void*)(lp), 16, 0, 0)

__global__ __launch_bounds__(256) void gemm_k(const u16* __restrict__ A,
                                              const u16* __restrict__ Bm,
                                              float* __restrict__ C){
  __shared__ __align__(16) u16 As[128 * 32];
  __shared__ __align__(16) u16 Bs[128 * 32];
  const int tid = threadIdx.x;
  const int w = tid >> 6, l = tid & 63;
  const int bid = blockIdx.x;
  const int mt = bid >> 4, nt = bid & 15;
  const int m0 = mt * 128, n0 = nt * 128;
  const int srow = tid >> 2;            // 0..63
  const int scol = (tid & 3) * 8;       // 0,8,16,24
  const int wr = w & 1, wc = w >> 1;
  const int lhi = l >> 4, llo = l & 15;

  f32x4 acc[4][4];
  #pragma unroll
  for (int i = 0; i < 4; i++)
    #pragma unroll
    for (int j = 0; j < 4; j++)
      acc[i][j] = (f32x4){0.f, 0.f, 0.f, 0.f};

  for (int kt = 0; kt < 96; ++kt){
    int k = kt * 32;
    int keff = (k >= 2048) ? (k - 2048) : k;
    #pragma unroll
    for (int r = 0; r < 2; r++){
      const u16* ga = A  + (size_t)(m0 + r * 64 + srow) * 2048 + keff + scol;
      GLDS(ga, &As[r * 2048 + w * 512]);
      const u16* gb = Bm + (size_t)(n0 + r * 64 + srow) * 3072 + k + scol;
      GLDS(gb, &Bs[r * 2048 + w * 512]);
    }
    __syncthreads();
    short8 af[4], bf[4];
    #pragma unroll
    for (int i = 0; i < 4; i++){
      af[i] = *(const short8*)&As[(wr * 64 + i * 16 + llo) * 32 + lhi * 8];
      bf[i] = *(const short8*)&Bs[(wc * 64 + i * 16 + llo) * 32 + lhi * 8];
    }
    #pragma unroll
    for (int i = 0; i < 4; i++)
      #pragma unroll
      for (int j = 0; j < 4; j++)
        acc[i][j] = __builtin_amdgcn_mfma_f32_16x16x32_bf16(af[i], bf[j], acc[i][j], 0, 0, 0);
    __syncthreads();
  }
  #pragma unroll
  for (int i = 0; i < 4; i++)
    #pragma unroll
    for (int j = 0; j < 4; j++)
      #pragma unroll
      for (int rg = 0; rg < 4; rg++){
        int mr = m0 + wr * 64 + i * 16 + lhi * 4 + rg;
        int nc = n0 + wc * 64 + j * 16 + llo;
        C[(size_t)mr * 2048 + nc] = acc[i][j][rg];
      }
}

// ---------------------------------------------------------------------------
// Sparse build: count nnz per row (one wave per row)
// ---------------------------------------------------------------------------
__global__ __launch_bounds__(256) void count_k(const float* __restrict__ W,
                                               int* __restrict__ nnz){
  int gt = blockIdx.x * 256 + threadIdx.x;
  int row = gt >> 6, l = gt & 63;
  const float* wr = W + (size_t)row * 2048;
  int c = 0;
  for (int i = 0; i < 32; i++) c += (wr[i * 64 + l] != 0.0f) ? 1 : 0;
  for (int off = 32; off; off >>= 1) c += __shfl_down(c, off, 64);
  if (l == 0) nnz[row] = c;
}

// ---------------------------------------------------------------------------
// Counting-sort rows desc by nnz, pair p <-> 2047-p (long with short)
// ---------------------------------------------------------------------------
__global__ __launch_bounds__(1024) void sort_k(const int* __restrict__ nnz,
                                               u32* __restrict__ rowsp,
                                               int* __restrict__ L1a){
  __shared__ int hist[64], off[64], cur[64];
  __shared__ int order[2048];
  int tid = threadIdx.x;
  if (tid < 64){ hist[tid] = 0; cur[tid] = 0; }
  __syncthreads();
  for (int r = tid; r < 2048; r += 1024){
    int b = nnz[r]; if (b > 63) b = 63;
    atomicAdd(&hist[b], 1);
  }
  __syncthreads();
  if (tid == 0){
    int run = 0;
    for (int b = 63; b >= 0; b--){ off[b] = run; run += hist[b]; }
  }
  __syncthreads();
  for (int r = tid; r < 2048; r += 1024){
    int b = nnz[r]; if (b > 63) b = 63;
    int pos = off[b] + atomicAdd(&cur[b], 1);
    order[pos] = r;
  }
  __syncthreads();
  int rA = order[tid], rB = order[2047 - tid];
  rowsp[tid] = (u32)rA | ((u32)rB << 16);
  L1a[tid] = nnz[rA];
}

// ---------------------------------------------------------------------------
// Fill per-thread chunks: one wave per pair; slots [0,L1): rowA, [L1,..): rowB
// layout val[slot*1024+p], col32[slot*1024+p]; pad to CAP with (0,0)
// ---------------------------------------------------------------------------
__global__ __launch_bounds__(256) void fill_k(const float* __restrict__ W,
                                              const u32* __restrict__ rowsp,
                                              float* __restrict__ valw,
                                              u32* __restrict__ col32){
  int gt = blockIdx.x * 256 + threadIdx.x;
  int p = gt >> 6, l = gt & 63;
  u32 rp = rowsp[p];
  int rA = (int)(rp & 0xffffu), rB = (int)(rp >> 16);
  int base = 0;
  for (int h = 0; h < 2; h++){
    int row = h ? rB : rA;
    const float* wr = W + (size_t)row * 2048;
    int cnt = 0;
    for (int i = 0; i < 32; i++){
      int c = i * 64 + l;
      float v = wr[c];
      unsigned long long m = __ballot(v != 0.0f);
      int pre = __popcll(m & ((1ull << l) - 1ull));
      if (v != 0.0f){
        int s = base + cnt + pre;
        if (s < CAP){
          valw[s * 1024 + p] = v;
          col32[s * 1024 + p] = (u32)c;
        }
      }
      cnt += __popcll(m);
    }
    base += cnt;
  }
  for (int s = base + l; s < CAP; s += 64){
    valw[s * 1024 + p] = 0.0f;
    col32[s * 1024 + p] = 0u;
  }
}

__global__ __launch_bounds__(256) void packc_k(const u32* __restrict__ c32,
                                               u32* __restrict__ cw){
  int idx = blockIdx.x * 256 + threadIdx.x;    // CAPW*1024
  int j = idx >> 10, p = idx & 1023;
  cw[j * 1024 + p] = (c32[(2 * j) * 1024 + p] & 0xffffu) | (c32[(2 * j + 1) * 1024 + p] << 16);
}

// ---------------------------------------------------------------------------
// Recurrent kernel: 16 WGs (one batch/CU), 1024 thr, state in LDS,
// sparse W in registers (CAP val + CAPW packed cols per thread)
// d_out holds drive on entry to row t; overwritten with state after step t.
// ---------------------------------------------------------------------------
__global__ __launch_bounds__(1024) void rnn_k(float* __restrict__ out,
                                              const float* __restrict__ init,
                                              const float* __restrict__ valw,
                                              const u32* __restrict__ cwg,
                                              const u32* __restrict__ rowsp,
                                              const int* __restrict__ L1a){
  const int tid = threadIdx.x, b = blockIdx.x;
  float val[CAP]; u32 cw[CAPW];
  #pragma unroll
  for (int k = 0; k < CAP; k++) val[k] = valw[k * 1024 + tid];
  #pragma unroll
  for (int j = 0; j < CAPW; j++) cw[j] = cwg[j * 1024 + tid];
  u32 rp = rowsp[tid];
  int rA = (int)(rp & 0xffffu), rB = (int)(rp >> 16);
  int L1 = L1a[tid];

  __shared__ float st[2048];
  st[tid]        = init[(size_t)b * 2048 + tid];
  st[tid + 1024] = init[(size_t)b * 2048 + tid + 1024];
  __syncthreads();

  float* ob = out + (size_t)b * 1024 * 2048;
  for (int t = 0; t < 1024; t++){
    float* orow = ob + (size_t)t * 2048;
    float dA = orow[rA];       // drive (prefetched; consumed after MAC phase)
    float dB = orow[rB];
    float aAll = 0.f, aA = 0.f;
    #pragma unroll
    for (int k = 0; k < CAP; k++){
      u32 col = (k & 1) ? (cw[k >> 1] >> 16) : (cw[k >> 1] & 0xffffu);
      float pv = val[k] * st[col];
      aAll += pv;
      aA += (k < L1) ? pv : 0.0f;
    }
    float aB = aAll - aA;
    __syncthreads();                       // all st reads done
    float sA = tanh_fast(aA + dA);
    float sB = tanh_fast(aB + dB);
    st[rA] = sA; st[rB] = sB;
    __syncthreads();                       // new state visible
    orow[rA] = sA;                         // stores drain under next MAC phase
    orow[rB] = sB;
  }
}

// ---------------------------------------------------------------------------
extern "C" void kernel_launch(void* const* d_in, const int* in_sizes, int n_in,
                              void* d_out, int out_size, void* d_ws, size_t ws_size,
                              hipStream_t stream) {
  const float* x    = (const float*)d_in[0];
  const float* fb   = (const float*)d_in[1];
  const float* init = (const float*)d_in[2];
  const float* Wres = (const float*)d_in[3];
  const float* Win  = (const float*)d_in[4];
  const float* Wfb  = (const float*)d_in[5];
  float* out = (float*)d_out;

  char* w8 = (char*)d_ws;
  u16*  A_pack = (u16*)(w8);                       // 16384*2048*2 = 67108864
  u16*  B_pack = (u16*)(w8 + 67108864);            // 2048*3072*2  = 12582912
  float* valw  = (float*)(w8 + 79691776);          // 52*1024*4    = 212992
  u32*  col32  = (u32*) (w8 + 79904768);           // 212992
  u32*  colw   = (u32*) (w8 + 80117760);           // 26*1024*4    = 106496
  int*  nnz    = (int*) (w8 + 80224256);           // 8192
  u32*  rowsp  = (u32*) (w8 + 80232448);           // 4096
  int*  L1a    = (int*) (w8 + 80236544);           // 4096

  pack_a_k<<<32768, 256, 0, stream>>>(x, fb, A_pack);
  pack_b_k<<<4096, 256, 0, stream>>>(Win, Wfb, B_pack);
  gemm_k<<<2048, 256, 0, stream>>>(A_pack, B_pack, out);
  count_k<<<512, 256, 0, stream>>>(Wres, nnz);
  sort_k<<<1, 1024, 0, stream>>>(nnz, rowsp, L1a);
  fill_k<<<256, 256, 0, stream>>>(Wres, rowsp, valw, col32);
  packc_k<<<(CAPW * 1024) / 256, 256, 0, stream>>>(col32, colw);
  rnn_k<<<16, 1024, 0, stream>>>(out, init, valw, colw, rowsp, L1a);
}